// Round 4
// baseline (391.129 us; speedup 1.0000x reference)
//
#include <hip/hip_runtime.h>
#include <hip/hip_fp16.h>
#include <math.h>

#define NEG_SLOPE 0.2f
#define CAP 64    // slots per dst; deg ~ Poisson(17), P(deg>64) ~ e^-41 per node
#define SCATB 2048  // scatter blocks inside ka_k: 8 XCD slice-groups x 256

static __device__ __forceinline__ void atomAdd(float* a, float v) {
    unsafeAtomicAdd(a, v);
}

// Edge-layout probe: int64 indices (<2^31) have all-zero odd 32-bit words.
static __device__ __forceinline__ bool edges_are_i64(const int* __restrict__ ei) {
    return (ei[1] | ei[3] | ei[5] | ei[7]) == 0;
}
static __device__ __forceinline__ int ldsrc(const int* __restrict__ ei, int e, int E, bool i64) {
    return i64 ? ei[2 * e] : ei[e];
}
static __device__ __forceinline__ int lddst(const int* __restrict__ ei, int e, int E, bool i64) {
    return i64 ? ei[2 * (E + e)] : ei[E + e];
}

// ---- partition_k: single-pass 8-way slice bucketing ----
// Reads the int64 edge list ONCE (was 8x rescan = 109 MB), packs (src|dst<<16)
// (both < 65536), stages per-slice lists in LDS, appends coalesced runs to 8
// per-slice global buckets. Slice g owns dst in [g*N/8,(g+1)*N/8) -- matches
// the XCD-local scatter below (boundary rounding only affects locality).
__global__ __launch_bounds__(256) void partition_k(const int* __restrict__ ei,
                                                   unsigned int* __restrict__ bkt,
                                                   int* __restrict__ cur,
                                                   int E, int N, int CAPB) {
    __shared__ int lcnt[8], lbase[8];
    __shared__ unsigned int lbuf[8][256];
    const int tid = threadIdx.x;
    const bool i64 = edges_are_i64(ei);
    const int ET = E + N;
    const float sliceScale = 8.0f / (float)N;
    for (int base = blockIdx.x * 256; base < ET; base += gridDim.x * 256) {
        if (tid < 8) lcnt[tid] = 0;
        __syncthreads();
        const int e = base + tid;
        if (e < ET) {
            int s, d;
            if (e < E) { s = ldsrc(ei, e, E, i64); d = lddst(ei, e, E, i64); }
            else       { s = d = e - E; }
            int g = (int)((float)d * sliceScale);
            g = g < 0 ? 0 : (g > 7 ? 7 : g);
            int pos = atomicAdd(&lcnt[g], 1);
            lbuf[g][pos] = (unsigned int)s | ((unsigned int)d << 16);
        }
        __syncthreads();
        if (tid < 8) lbase[tid] = atomicAdd(&cur[tid], lcnt[tid]);
        __syncthreads();
        for (int g = 0; g < 8; ++g) {
            const int n = lcnt[g], b = lbase[g];
            for (int i = tid; i < n; i += 256) {
                const int idx = b + i;
                if (idx < CAPB) bkt[(size_t)g * CAPB + idx] = lbuf[g][i];
            }
        }
        __syncthreads();
    }
}

// ---- ka_k: gemm1 (blocks < G1) fused with XCD-local bucket scatter ----
// The two are independent; fusing overlaps gemm1's VALU work with scatter's
// atomic/latency-bound slot writes in one dispatch. Scatter blocks: grp =
// blockIdx&7 -> one XCD per slice (round-robin heuristic); that XCD's col
// slice (800 KB ushort) + deg slice (25 KB) stay L2-resident.
__global__ __launch_bounds__(256, 4) void ka_k(const float* __restrict__ x,
                                               const float* __restrict__ W,
                                               const float* __restrict__ aws,
                                               const float* __restrict__ awd,
                                               __half* __restrict__ h,
                                               float* __restrict__ as_,
                                               float* __restrict__ ad_,
                                               const unsigned int* __restrict__ bkt,
                                               const int* __restrict__ cur,
                                               int* __restrict__ deg,
                                               unsigned short* __restrict__ col,
                                               int N, int G1, int CAPB) {
    __shared__ float Ws[64 * 128];   // 32 KB, [k][j]
    __shared__ float xs[32 * 64];    // 8 KB, [row][k]
    const int tid = threadIdx.x;
    if ((int)blockIdx.x >= G1) {
        // ---- bucket scatter ----
        const int grp = blockIdx.x & 7;
        const int bin = (blockIdx.x - G1) >> 3;
        const int nb  = (gridDim.x - G1) >> 3;
        int cnt = cur[grp]; if (cnt > CAPB) cnt = CAPB;
        const unsigned int* bk = bkt + (size_t)grp * CAPB;
        for (int i = bin * 256 + tid; i < cnt; i += nb * 256) {
            const unsigned int u = bk[i];
            const int d = (int)(u >> 16), s = (int)(u & 0xFFFFu);
            int pos = atomicAdd(&deg[d], 1);
            if (pos < CAP) col[d * CAP + pos] = (unsigned short)s;
        }
        return;
    }
    // ---- gemm1: 4x4 register tile, 32-row blocks, fused att logits ----
    const int cg = tid & 31, rg = tid >> 5;
    const int r0 = blockIdx.x * 32;
#pragma unroll 1
    for (int i = tid; i < 8192; i += 256) Ws[i] = W[i];
    {
        const float* src = x + (size_t)r0 * 64;
        const int limit = (N - r0) * 64;
#pragma unroll 1
        for (int i = tid * 4; i < 2048; i += 1024) {
            float4 v = (i < limit) ? *(const float4*)(src + i) : make_float4(0, 0, 0, 0);
            *(float4*)(xs + i) = v;
        }
    }
    __syncthreads();

    float acc[4][4] = {};
#pragma unroll 2
    for (int k = 0; k < 64; k += 4) {
        float4 w0 = *(const float4*)(Ws + (k + 0) * 128 + cg * 4);
        float4 w1 = *(const float4*)(Ws + (k + 1) * 128 + cg * 4);
        float4 w2 = *(const float4*)(Ws + (k + 2) * 128 + cg * 4);
        float4 w3 = *(const float4*)(Ws + (k + 3) * 128 + cg * 4);
        float4 xv[4];
#pragma unroll
        for (int q = 0; q < 4; ++q) xv[q] = *(const float4*)(xs + (rg * 4 + q) * 64 + k);
#pragma unroll
        for (int q = 0; q < 4; ++q) {
            float4 xq = xv[q];
            acc[q][0] += xq.x * w0.x + xq.y * w1.x + xq.z * w2.x + xq.w * w3.x;
            acc[q][1] += xq.x * w0.y + xq.y * w1.y + xq.z * w2.y + xq.w * w3.y;
            acc[q][2] += xq.x * w0.z + xq.y * w1.z + xq.z * w2.z + xq.w * w3.z;
            acc[q][3] += xq.x * w0.w + xq.y * w1.w + xq.z * w2.w + xq.w * w3.w;
        }
    }

    const int jbase = cg * 4;
    const int head = cg >> 3;
    const float a0 = aws[jbase], a1 = aws[jbase + 1], a2 = aws[jbase + 2], a3 = aws[jbase + 3];
    const float d0 = awd[jbase], d1 = awd[jbase + 1], d2 = awd[jbase + 2], d3 = awd[jbase + 3];
    float ps[4], pd[4];
#pragma unroll
    for (int q = 0; q < 4; ++q) {
        ps[q] = acc[q][0] * a0 + acc[q][1] * a1 + acc[q][2] * a2 + acc[q][3] * a3;
        pd[q] = acc[q][0] * d0 + acc[q][1] * d1 + acc[q][2] * d2 + acc[q][3] * d3;
        int row = r0 + rg * 4 + q;
        if (row < N) {
            __half hv[4];
            hv[0] = __float2half(acc[q][0]); hv[1] = __float2half(acc[q][1]);
            hv[2] = __float2half(acc[q][2]); hv[3] = __float2half(acc[q][3]);
            *(uint2*)(h + (size_t)row * 128 + jbase) = *(uint2*)hv;
        }
    }
#pragma unroll
    for (int off = 4; off; off >>= 1) {
#pragma unroll
        for (int q = 0; q < 4; ++q) {
            ps[q] += __shfl_down(ps[q], off, 8);
            pd[q] += __shfl_down(pd[q], off, 8);
        }
    }
    if ((cg & 7) == 0) {
#pragma unroll
        for (int q = 0; q < 4; ++q) {
            int row = r0 + rg * 4 + q;
            if (row < N) { as_[row * 4 + head] = ps[q]; ad_[row * 4 + head] = pd[q]; }
        }
    }
}

// ---- gemm2: 4x4 register tile, 128-row blocks, fp16 in/out, k split 2x64 ----
__global__ __launch_bounds__(256, 4) void gemm2_k(const __half* __restrict__ hact,
                                                  const float* __restrict__ W,
                                                  const float* __restrict__ aws,
                                                  const float* __restrict__ awd,
                                                  __half* __restrict__ h2,
                                                  float* __restrict__ as_,
                                                  float* __restrict__ ad_, int N) {
    __shared__ float Ws[128 * 32];     // 16 KB, [k][j]
    __shared__ float xs[128 * 68];     // 34 KB, [row][k], stride 68
    const int tid = threadIdx.x;
    const int cg = tid & 7, rg = tid >> 3;
    const int r0 = blockIdx.x * 128;
    for (int i = tid; i < 4096; i += 256) Ws[i] = W[i];

    float acc[4][4] = {};
#pragma unroll 1
    for (int p = 0; p < 2; ++p) {
        __syncthreads();
#pragma unroll 2
        for (int i = tid * 4; i < 8192; i += 1024) {
            int row = i >> 6, kk = i & 63;
            float4 v = make_float4(0, 0, 0, 0);
            if (r0 + row < N) {
                uint2 hv = *(const uint2*)(hact + (size_t)(r0 + row) * 128 + p * 64 + kk);
                const __half2* ph = (const __half2*)&hv;
                float2 f0 = __half22float2(ph[0]);
                float2 f1 = __half22float2(ph[1]);
                v = make_float4(f0.x, f0.y, f1.x, f1.y);
            }
            *(float4*)(xs + row * 68 + kk) = v;
        }
        __syncthreads();
#pragma unroll 2
        for (int k = 0; k < 64; k += 4) {
            float4 w0 = *(const float4*)(Ws + (p * 64 + k + 0) * 32 + cg * 4);
            float4 w1 = *(const float4*)(Ws + (p * 64 + k + 1) * 32 + cg * 4);
            float4 w2 = *(const float4*)(Ws + (p * 64 + k + 2) * 32 + cg * 4);
            float4 w3 = *(const float4*)(Ws + (p * 64 + k + 3) * 32 + cg * 4);
            float4 xv[4];
#pragma unroll
            for (int q = 0; q < 4; ++q) xv[q] = *(const float4*)(xs + (rg * 4 + q) * 68 + k);
#pragma unroll
            for (int q = 0; q < 4; ++q) {
                float4 xq = xv[q];
                acc[q][0] += xq.x * w0.x + xq.y * w1.x + xq.z * w2.x + xq.w * w3.x;
                acc[q][1] += xq.x * w0.y + xq.y * w1.y + xq.z * w2.y + xq.w * w3.y;
                acc[q][2] += xq.x * w0.z + xq.y * w1.z + xq.z * w2.z + xq.w * w3.z;
                acc[q][3] += xq.x * w0.w + xq.y * w1.w + xq.z * w2.w + xq.w * w3.w;
            }
        }
    }

    const int jbase = cg * 4;
    const float a0 = aws[jbase], a1 = aws[jbase + 1], a2 = aws[jbase + 2], a3 = aws[jbase + 3];
    const float d0 = awd[jbase], d1 = awd[jbase + 1], d2 = awd[jbase + 2], d3 = awd[jbase + 3];
    float ps[4], pd[4];
#pragma unroll
    for (int q = 0; q < 4; ++q) {
        ps[q] = acc[q][0] * a0 + acc[q][1] * a1 + acc[q][2] * a2 + acc[q][3] * a3;
        pd[q] = acc[q][0] * d0 + acc[q][1] * d1 + acc[q][2] * d2 + acc[q][3] * d3;
        int row = r0 + rg * 4 + q;
        if (row < N) {
            __half hv[4];
            hv[0] = __float2half(acc[q][0]); hv[1] = __float2half(acc[q][1]);
            hv[2] = __float2half(acc[q][2]); hv[3] = __float2half(acc[q][3]);
            *(uint2*)(h2 + (size_t)row * 32 + jbase) = *(uint2*)hv;
        }
    }
#pragma unroll
    for (int off = 4; off; off >>= 1) {
#pragma unroll
        for (int q = 0; q < 4; ++q) {
            ps[q] += __shfl_down(ps[q], off, 8);
            pd[q] += __shfl_down(pd[q], off, 8);
        }
    }
    if (cg == 0) {
#pragma unroll
        for (int q = 0; q < 4; ++q) {
            int row = r0 + rg * 4 + q;
            if (row < N) { as_[row] = ps[q]; ad_[row] = pd[q]; }
        }
    }
}

// ---- pull L1 batch body: NB outstanding gathers, straight-line ----
template <int NB>
static __device__ __forceinline__ void p1_batch(int s, float p, const __half* __restrict__ h,
                                                int lane, float& acc0, float& acc1) {
    int su[NB];
#pragma unroll
    for (int u = 0; u < NB; ++u) su[u] = __shfl(s, u, 16);
    __half2 g[NB];
#pragma unroll
    for (int u = 0; u < NB; ++u) g[u] = *(const __half2*)(h + (size_t)su[u] * 128 + lane * 2);
    float pu[NB];
#pragma unroll
    for (int u = 0; u < NB; ++u) pu[u] = __shfl(p, u, 16);
#pragma unroll
    for (int u = 0; u < NB; ++u) {
        float2 gf = __half22float2(g[u]);
        acc0 += pu[u] * gf.x; acc1 += pu[u] * gf.y;
    }
}

// ---- pull aggregation L1: tiered 16/8/4 batches, masked straight-line ----
__global__ __launch_bounds__(256) void pull_agg1_k(const int* __restrict__ deg,
                                                   const unsigned short* __restrict__ col,
                                                   const float* __restrict__ asrc,
                                                   const float* __restrict__ adst,
                                                   const __half* __restrict__ h,
                                                   const float* __restrict__ b1,
                                                   __half* __restrict__ hact, int N) {
    int wave = (blockIdx.x * 256 + threadIdx.x) >> 6;
    int lane = threadIdx.x & 63;
    if (wave >= N) return;
    const int d = wave;
    const int hd = lane >> 4;     // head: p-compute AND channel accumulation
    const int el = lane & 15;     // edge slot within a 16-edge batch
    const float ad = adst[d * 4 + hd];
    const unsigned short* cl = col + d * CAP;
    int cnt = deg[d]; if (cnt > CAP) cnt = CAP;
    float acc0 = 0.0f, acc1 = 0.0f, den = 0.0f;

    for (int i = 0; i < cnt; i += 16) {
        const int r = cnt - i;               // wave-uniform
        int s = 0; float p = 0.0f;
        if (el < r) {
            s = cl[i + el];
            float v = asrc[s * 4 + hd] + ad;
            v = v > 0.0f ? v : NEG_SLOPE * v;
            p = __expf(v);
        }
        den += p;
        if (r >= 9)      p1_batch<16>(s, p, h, lane, acc0, acc1);
        else if (r >= 5) p1_batch<8>(s, p, h, lane, acc0, acc1);
        else             p1_batch<4>(s, p, h, lane, acc0, acc1);
    }
    // den: reduce across the 16 lanes of this head group
    den += __shfl_xor(den, 1, 16);
    den += __shfl_xor(den, 2, 16);
    den += __shfl_xor(den, 4, 16);
    den += __shfl_xor(den, 8, 16);

    float inv = 1.0f / den;                  // den>0: self-loop guaranteed
    float o0 = acc0 * inv + b1[lane * 2];
    float o1 = acc1 * inv + b1[lane * 2 + 1];
    o0 = o0 > 0.0f ? o0 : expm1f(o0);
    o1 = o1 > 0.0f ? o1 : expm1f(o1);
    *(__half2*)(hact + (size_t)d * 128 + lane * 2) = __floats2half2_rn(o0, o1);
}

// ---- pull L2 batch body ----
template <int NB>
static __device__ __forceinline__ void p2_batch(int s, float p, const __half* __restrict__ h,
                                                int lane, float& acc) {
    int su[NB];
#pragma unroll
    for (int u = 0; u < NB; ++u) su[u] = __shfl(s, u, 16);
    __half g[NB];
#pragma unroll
    for (int u = 0; u < NB; ++u) g[u] = h[(size_t)su[u] * 32 + lane];
    float pu[NB];
#pragma unroll
    for (int u = 0; u < NB; ++u) pu[u] = __shfl(p, u, 16);
#pragma unroll
    for (int u = 0; u < NB; ++u) acc += pu[u] * __half2float(g[u]);
}

// ---- pull aggregation L2 (H=1,C=32) + fused column-mean + fused final ----
// Grid-stride over dsts; column partials in registers -> LDS reduce -> 32
// atomics per block. Last-block-done pattern then computes the readout in
// this same dispatch (counter at gsum[32]; atomic reads of gsum for
// cross-XCD visibility).
__global__ __launch_bounds__(256) void pull_agg2_k(const int* __restrict__ deg,
                                                   const unsigned short* __restrict__ col,
                                                   const float* __restrict__ asrc,
                                                   const float* __restrict__ adst,
                                                   const __half* __restrict__ h,
                                                   float* __restrict__ gsum,
                                                   int* __restrict__ counter,
                                                   const float* __restrict__ b2w,
                                                   const float* __restrict__ linW,
                                                   const float* __restrict__ linb,
                                                   float* __restrict__ out, int N) {
    const int tid = threadIdx.x;
    const int lane = tid & 31;
    const int el = lane & 15;
    const int gloc = tid >> 5;                   // 8 dst-groups per block
    float csum = 0.0f;
    for (int d = blockIdx.x * 8 + gloc; d < N; d += gridDim.x * 8) {
        const float ad = adst[d];
        const unsigned short* cl = col + d * CAP;
        int cnt = deg[d]; if (cnt > CAP) cnt = CAP;
        float acc = 0.0f, den = 0.0f;
        for (int i = 0; i < cnt; i += 16) {
            const int r = cnt - i;
            int s = 0; float p = 0.0f;
            if (el < r) {
                s = cl[i + el];
                float v = asrc[s] + ad;
                v = v > 0.0f ? v : NEG_SLOPE * v;
                p = __expf(v);
            }
            den += p;                            // both halves identical; reduce width 16
            if (r >= 9)      p2_batch<16>(s, p, h, lane, acc);
            else if (r >= 5) p2_batch<8>(s, p, h, lane, acc);
            else             p2_batch<4>(s, p, h, lane, acc);
        }
        den += __shfl_xor(den, 1, 16);
        den += __shfl_xor(den, 2, 16);
        den += __shfl_xor(den, 4, 16);
        den += __shfl_xor(den, 8, 16);
        csum += acc / den;
    }
    __shared__ float lds[256];
    lds[tid] = csum;
    __syncthreads();
    if (tid < 32) {
        float s2 = 0.0f;
#pragma unroll
        for (int g = 0; g < 8; ++g) s2 += lds[g * 32 + tid];
        atomAdd(&gsum[tid], s2);
    }
    // ---- last-block-done readout ----
    __threadfence();
    __syncthreads();
    __shared__ int isLast;
    if (tid == 0) isLast = (atomicAdd(counter, 1) == (int)gridDim.x - 1);
    __syncthreads();
    if (isLast) {
        __shared__ float gv[32];
        if (tid < 32) gv[tid] = unsafeAtomicAdd(&gsum[tid], 0.0f);  // coherent read
        __syncthreads();
        if (tid == 0) {
            float g[32];
#pragma unroll
            for (int c = 0; c < 32; ++c) g[c] = gv[c] / (float)N + b2w[c];
            float lo[3];
#pragma unroll
            for (int j = 0; j < 3; ++j) {
                float acc = linb[j];
#pragma unroll
                for (int c = 0; c < 32; ++c) acc += g[c] * linW[c * 3 + j];
                lo[j] = acc;
            }
            float mx = fmaxf(lo[0], fmaxf(lo[1], lo[2]));
            float ex[3], se = 0.0f;
#pragma unroll
            for (int j = 0; j < 3; ++j) { ex[j] = __expf(lo[j] - mx); se += ex[j]; }
#pragma unroll
            for (int j = 0; j < 3; ++j) out[j] = ex[j] / se;
        }
    }
}

extern "C" void kernel_launch(void* const* d_in, const int* in_sizes, int n_in,
                              void* d_out, int out_size, void* d_ws, size_t ws_size,
                              hipStream_t stream) {
    const float* x    = (const float*)d_in[0];
    const float* W1   = (const float*)d_in[1];
    const float* as1w = (const float*)d_in[2];
    const float* ad1w = (const float*)d_in[3];
    const float* b1   = (const float*)d_in[4];
    const float* W2   = (const float*)d_in[5];
    const float* as2w = (const float*)d_in[6];
    const float* ad2w = (const float*)d_in[7];
    const float* b2w  = (const float*)d_in[8];
    const float* linW = (const float*)d_in[9];
    const float* linb = (const float*)d_in[10];
    const int*   ei   = (const int*)d_in[11];

    const int N = in_sizes[0] / 64;       // 50000
    const int E = in_sizes[11] / 2;       // 800000
    const int CAPB = (E + N) / 8 + 8192;  // per-slice bucket capacity

    float* ws = (float*)d_ws;
    __half* h1h   = (__half*)ws;                         // N*128 halves
    __half* hacth = (__half*)(ws + (size_t)N * 64);      // N*128 halves
    float* asrc1 = ws + (size_t)N * 128;                 // N*4
    float* adst1 = asrc1 + (size_t)N * 4;                // N*4
    float* asrc2 = adst1 + (size_t)N * 4;                // N
    float* adst2 = asrc2 + (size_t)N;                    // N
    float* gsum  = adst2 + (size_t)N;                    // 32 + counter
    int* counter = (int*)(gsum + 32);                    // 1
    int* cur     = (int*)(gsum + 33);                    // 8 bucket cursors
    int* deg     = cur + 8;                              // N
    unsigned short* col = (unsigned short*)(deg + N);    // N*CAP ushorts
    unsigned int* bkt = (unsigned int*)(col + (size_t)N * CAP);  // 8*CAPB
    // layer-2 alias inside h1h region (dead after pull_agg1):
    __half* h2h  = (__half*)ws;                          // N*32 halves

    auto cdiv = [](int a, int b) { return (a + b - 1) / b; };
    const int G1 = cdiv(N, 32);

    hipMemsetAsync(deg, 0, (size_t)N * sizeof(int), stream);
    hipMemsetAsync(gsum, 0, 41 * sizeof(float), stream);  // gsum + counter + cur

    // ---- single-pass edge partition into 8 XCD slice buckets ----
    partition_k<<<1024, 256, 0, stream>>>(ei, bkt, cur, E, N, CAPB);

    // ---- gemm1 || XCD-local bucket scatter (one dispatch) ----
    ka_k<<<G1 + SCATB, 256, 0, stream>>>(x, W1, as1w, ad1w, h1h, asrc1, adst1,
                                         bkt, cur, deg, col, N, G1, CAPB);

    // ---- layer 1 aggregation ----
    pull_agg1_k<<<cdiv(N, 4), 256, 0, stream>>>(deg, col, asrc1, adst1, h1h, b1, hacth, N);

    // ---- layer 2 ----
    gemm2_k<<<cdiv(N, 128), 256, 0, stream>>>(hacth, W2, as2w, ad2w, h2h, asrc2, adst2, N);
    pull_agg2_k<<<2048, 256, 0, stream>>>(deg, col, asrc2, adst2, h2h, gsum, counter,
                                          b2w, linW, linb, (float*)d_out, N);
}

// Round 5
// 278.395 us; speedup vs baseline: 1.4049x; 1.4049x over previous
//
#include <hip/hip_runtime.h>
#include <hip/hip_fp16.h>
#include <math.h>

#define NEG_SLOPE 0.2f
#define CAP 64    // slots per dst; deg ~ Poisson(17), P(deg>64) ~ e^-41 per node
#define SCATB 2048  // scatter blocks inside ka_k: 8 XCD slice-groups x 256

static __device__ __forceinline__ void atomAdd(float* a, float v) {
    unsafeAtomicAdd(a, v);
}

// Edge-layout probe: int64 indices (<2^31) have all-zero odd 32-bit words.
static __device__ __forceinline__ bool edges_are_i64(const int* __restrict__ ei) {
    return (ei[1] | ei[3] | ei[5] | ei[7]) == 0;
}
static __device__ __forceinline__ int ldsrc(const int* __restrict__ ei, int e, int E, bool i64) {
    return i64 ? ei[2 * e] : ei[e];
}
static __device__ __forceinline__ int lddst(const int* __restrict__ ei, int e, int E, bool i64) {
    return i64 ? ei[2 * (E + e)] : ei[E + e];
}

// ---- partition_k: single-pass 8-way slice bucketing ----
// Reads the int64 edge list ONCE (was 8x rescan = 109 MB), packs (src|dst<<16)
// (both < 65536), stages per-slice lists in LDS, appends coalesced runs to 8
// per-slice global buckets. Slice g owns dst in [g*N/8,(g+1)*N/8) -- matches
// the XCD-local scatter below (boundary rounding only affects locality).
__global__ __launch_bounds__(256) void partition_k(const int* __restrict__ ei,
                                                   unsigned int* __restrict__ bkt,
                                                   int* __restrict__ cur,
                                                   int E, int N, int CAPB) {
    __shared__ int lcnt[8], lbase[8];
    __shared__ unsigned int lbuf[8][256];
    const int tid = threadIdx.x;
    const bool i64 = edges_are_i64(ei);
    const int ET = E + N;
    const float sliceScale = 8.0f / (float)N;
    for (int base = blockIdx.x * 256; base < ET; base += gridDim.x * 256) {
        if (tid < 8) lcnt[tid] = 0;
        __syncthreads();
        const int e = base + tid;
        if (e < ET) {
            int s, d;
            if (e < E) { s = ldsrc(ei, e, E, i64); d = lddst(ei, e, E, i64); }
            else       { s = d = e - E; }
            int g = (int)((float)d * sliceScale);
            g = g < 0 ? 0 : (g > 7 ? 7 : g);
            int pos = atomicAdd(&lcnt[g], 1);
            lbuf[g][pos] = (unsigned int)s | ((unsigned int)d << 16);
        }
        __syncthreads();
        if (tid < 8) lbase[tid] = atomicAdd(&cur[tid], lcnt[tid]);
        __syncthreads();
        for (int g = 0; g < 8; ++g) {
            const int n = lcnt[g], b = lbase[g];
            for (int i = tid; i < n; i += 256) {
                const int idx = b + i;
                if (idx < CAPB) bkt[(size_t)g * CAPB + idx] = lbuf[g][i];
            }
        }
        __syncthreads();
    }
}

// ---- ka_k: gemm1 (blocks < G1) fused with XCD-local bucket scatter ----
// The two are independent; fusing overlaps gemm1's VALU work with scatter's
// atomic/latency-bound slot writes in one dispatch. Scatter blocks: grp =
// blockIdx&7 -> one XCD per slice (round-robin heuristic); that XCD's col
// slice (800 KB ushort) + deg slice (25 KB) stay L2-resident.
__global__ __launch_bounds__(256, 4) void ka_k(const float* __restrict__ x,
                                               const float* __restrict__ W,
                                               const float* __restrict__ aws,
                                               const float* __restrict__ awd,
                                               __half* __restrict__ h,
                                               float* __restrict__ as_,
                                               float* __restrict__ ad_,
                                               const unsigned int* __restrict__ bkt,
                                               const int* __restrict__ cur,
                                               int* __restrict__ deg,
                                               unsigned short* __restrict__ col,
                                               int N, int G1, int CAPB) {
    __shared__ float Ws[64 * 128];   // 32 KB, [k][j]
    __shared__ float xs[32 * 64];    // 8 KB, [row][k]
    const int tid = threadIdx.x;
    if ((int)blockIdx.x >= G1) {
        // ---- bucket scatter ----
        const int grp = blockIdx.x & 7;
        const int bin = (blockIdx.x - G1) >> 3;
        const int nb  = (gridDim.x - G1) >> 3;
        int cnt = cur[grp]; if (cnt > CAPB) cnt = CAPB;
        const unsigned int* bk = bkt + (size_t)grp * CAPB;
        for (int i = bin * 256 + tid; i < cnt; i += nb * 256) {
            const unsigned int u = bk[i];
            const int d = (int)(u >> 16), s = (int)(u & 0xFFFFu);
            int pos = atomicAdd(&deg[d], 1);
            if (pos < CAP) col[d * CAP + pos] = (unsigned short)s;
        }
        return;
    }
    // ---- gemm1: 4x4 register tile, 32-row blocks, fused att logits ----
    const int cg = tid & 31, rg = tid >> 5;
    const int r0 = blockIdx.x * 32;
#pragma unroll 1
    for (int i = tid; i < 8192; i += 256) Ws[i] = W[i];
    {
        const float* src = x + (size_t)r0 * 64;
        const int limit = (N - r0) * 64;
#pragma unroll 1
        for (int i = tid * 4; i < 2048; i += 1024) {
            float4 v = (i < limit) ? *(const float4*)(src + i) : make_float4(0, 0, 0, 0);
            *(float4*)(xs + i) = v;
        }
    }
    __syncthreads();

    float acc[4][4] = {};
#pragma unroll 2
    for (int k = 0; k < 64; k += 4) {
        float4 w0 = *(const float4*)(Ws + (k + 0) * 128 + cg * 4);
        float4 w1 = *(const float4*)(Ws + (k + 1) * 128 + cg * 4);
        float4 w2 = *(const float4*)(Ws + (k + 2) * 128 + cg * 4);
        float4 w3 = *(const float4*)(Ws + (k + 3) * 128 + cg * 4);
        float4 xv[4];
#pragma unroll
        for (int q = 0; q < 4; ++q) xv[q] = *(const float4*)(xs + (rg * 4 + q) * 64 + k);
#pragma unroll
        for (int q = 0; q < 4; ++q) {
            float4 xq = xv[q];
            acc[q][0] += xq.x * w0.x + xq.y * w1.x + xq.z * w2.x + xq.w * w3.x;
            acc[q][1] += xq.x * w0.y + xq.y * w1.y + xq.z * w2.y + xq.w * w3.y;
            acc[q][2] += xq.x * w0.z + xq.y * w1.z + xq.z * w2.z + xq.w * w3.z;
            acc[q][3] += xq.x * w0.w + xq.y * w1.w + xq.z * w2.w + xq.w * w3.w;
        }
    }

    const int jbase = cg * 4;
    const int head = cg >> 3;
    const float a0 = aws[jbase], a1 = aws[jbase + 1], a2 = aws[jbase + 2], a3 = aws[jbase + 3];
    const float d0 = awd[jbase], d1 = awd[jbase + 1], d2 = awd[jbase + 2], d3 = awd[jbase + 3];
    float ps[4], pd[4];
#pragma unroll
    for (int q = 0; q < 4; ++q) {
        ps[q] = acc[q][0] * a0 + acc[q][1] * a1 + acc[q][2] * a2 + acc[q][3] * a3;
        pd[q] = acc[q][0] * d0 + acc[q][1] * d1 + acc[q][2] * d2 + acc[q][3] * d3;
        int row = r0 + rg * 4 + q;
        if (row < N) {
            __half hv[4];
            hv[0] = __float2half(acc[q][0]); hv[1] = __float2half(acc[q][1]);
            hv[2] = __float2half(acc[q][2]); hv[3] = __float2half(acc[q][3]);
            *(uint2*)(h + (size_t)row * 128 + jbase) = *(uint2*)hv;
        }
    }
#pragma unroll
    for (int off = 4; off; off >>= 1) {
#pragma unroll
        for (int q = 0; q < 4; ++q) {
            ps[q] += __shfl_down(ps[q], off, 8);
            pd[q] += __shfl_down(pd[q], off, 8);
        }
    }
    if ((cg & 7) == 0) {
#pragma unroll
        for (int q = 0; q < 4; ++q) {
            int row = r0 + rg * 4 + q;
            if (row < N) { as_[row * 4 + head] = ps[q]; ad_[row * 4 + head] = pd[q]; }
        }
    }
}

// ---- gemm2: 4x4 register tile, 128-row blocks, fp16 in/out, k split 2x64 ----
__global__ __launch_bounds__(256, 4) void gemm2_k(const __half* __restrict__ hact,
                                                  const float* __restrict__ W,
                                                  const float* __restrict__ aws,
                                                  const float* __restrict__ awd,
                                                  __half* __restrict__ h2,
                                                  float* __restrict__ as_,
                                                  float* __restrict__ ad_, int N) {
    __shared__ float Ws[128 * 32];     // 16 KB, [k][j]
    __shared__ float xs[128 * 68];     // 34 KB, [row][k], stride 68
    const int tid = threadIdx.x;
    const int cg = tid & 7, rg = tid >> 3;
    const int r0 = blockIdx.x * 128;
    for (int i = tid; i < 4096; i += 256) Ws[i] = W[i];

    float acc[4][4] = {};
#pragma unroll 1
    for (int p = 0; p < 2; ++p) {
        __syncthreads();
#pragma unroll 2
        for (int i = tid * 4; i < 8192; i += 1024) {
            int row = i >> 6, kk = i & 63;
            float4 v = make_float4(0, 0, 0, 0);
            if (r0 + row < N) {
                uint2 hv = *(const uint2*)(hact + (size_t)(r0 + row) * 128 + p * 64 + kk);
                const __half2* ph = (const __half2*)&hv;
                float2 f0 = __half22float2(ph[0]);
                float2 f1 = __half22float2(ph[1]);
                v = make_float4(f0.x, f0.y, f1.x, f1.y);
            }
            *(float4*)(xs + row * 68 + kk) = v;
        }
        __syncthreads();
#pragma unroll 2
        for (int k = 0; k < 64; k += 4) {
            float4 w0 = *(const float4*)(Ws + (p * 64 + k + 0) * 32 + cg * 4);
            float4 w1 = *(const float4*)(Ws + (p * 64 + k + 1) * 32 + cg * 4);
            float4 w2 = *(const float4*)(Ws + (p * 64 + k + 2) * 32 + cg * 4);
            float4 w3 = *(const float4*)(Ws + (p * 64 + k + 3) * 32 + cg * 4);
            float4 xv[4];
#pragma unroll
            for (int q = 0; q < 4; ++q) xv[q] = *(const float4*)(xs + (rg * 4 + q) * 68 + k);
#pragma unroll
            for (int q = 0; q < 4; ++q) {
                float4 xq = xv[q];
                acc[q][0] += xq.x * w0.x + xq.y * w1.x + xq.z * w2.x + xq.w * w3.x;
                acc[q][1] += xq.x * w0.y + xq.y * w1.y + xq.z * w2.y + xq.w * w3.y;
                acc[q][2] += xq.x * w0.z + xq.y * w1.z + xq.z * w2.z + xq.w * w3.z;
                acc[q][3] += xq.x * w0.w + xq.y * w1.w + xq.z * w2.w + xq.w * w3.w;
            }
        }
    }

    const int jbase = cg * 4;
    const float a0 = aws[jbase], a1 = aws[jbase + 1], a2 = aws[jbase + 2], a3 = aws[jbase + 3];
    const float d0 = awd[jbase], d1 = awd[jbase + 1], d2 = awd[jbase + 2], d3 = awd[jbase + 3];
    float ps[4], pd[4];
#pragma unroll
    for (int q = 0; q < 4; ++q) {
        ps[q] = acc[q][0] * a0 + acc[q][1] * a1 + acc[q][2] * a2 + acc[q][3] * a3;
        pd[q] = acc[q][0] * d0 + acc[q][1] * d1 + acc[q][2] * d2 + acc[q][3] * d3;
        int row = r0 + rg * 4 + q;
        if (row < N) {
            __half hv[4];
            hv[0] = __float2half(acc[q][0]); hv[1] = __float2half(acc[q][1]);
            hv[2] = __float2half(acc[q][2]); hv[3] = __float2half(acc[q][3]);
            *(uint2*)(h2 + (size_t)row * 32 + jbase) = *(uint2*)hv;
        }
    }
#pragma unroll
    for (int off = 4; off; off >>= 1) {
#pragma unroll
        for (int q = 0; q < 4; ++q) {
            ps[q] += __shfl_down(ps[q], off, 8);
            pd[q] += __shfl_down(pd[q], off, 8);
        }
    }
    if (cg == 0) {
#pragma unroll
        for (int q = 0; q < 4; ++q) {
            int row = r0 + rg * 4 + q;
            if (row < N) { as_[row] = ps[q]; ad_[row] = pd[q]; }
        }
    }
}

// ---- pull L1 batch body: NB outstanding gathers, straight-line ----
template <int NB>
static __device__ __forceinline__ void p1_batch(int s, float p, const __half* __restrict__ h,
                                                int lane, float& acc0, float& acc1) {
    int su[NB];
#pragma unroll
    for (int u = 0; u < NB; ++u) su[u] = __shfl(s, u, 16);
    __half2 g[NB];
#pragma unroll
    for (int u = 0; u < NB; ++u) g[u] = *(const __half2*)(h + (size_t)su[u] * 128 + lane * 2);
    float pu[NB];
#pragma unroll
    for (int u = 0; u < NB; ++u) pu[u] = __shfl(p, u, 16);
#pragma unroll
    for (int u = 0; u < NB; ++u) {
        float2 gf = __half22float2(g[u]);
        acc0 += pu[u] * gf.x; acc1 += pu[u] * gf.y;
    }
}

// ---- pull aggregation L1: tiered 16/8/4 batches, masked straight-line ----
__global__ __launch_bounds__(256) void pull_agg1_k(const int* __restrict__ deg,
                                                   const unsigned short* __restrict__ col,
                                                   const float* __restrict__ asrc,
                                                   const float* __restrict__ adst,
                                                   const __half* __restrict__ h,
                                                   const float* __restrict__ b1,
                                                   __half* __restrict__ hact, int N) {
    int wave = (blockIdx.x * 256 + threadIdx.x) >> 6;
    int lane = threadIdx.x & 63;
    if (wave >= N) return;
    const int d = wave;
    const int hd = lane >> 4;     // head: p-compute AND channel accumulation
    const int el = lane & 15;     // edge slot within a 16-edge batch
    const float ad = adst[d * 4 + hd];
    const unsigned short* cl = col + d * CAP;
    int cnt = deg[d]; if (cnt > CAP) cnt = CAP;
    float acc0 = 0.0f, acc1 = 0.0f, den = 0.0f;

    for (int i = 0; i < cnt; i += 16) {
        const int r = cnt - i;               // wave-uniform
        int s = 0; float p = 0.0f;
        if (el < r) {
            s = cl[i + el];
            float v = asrc[s * 4 + hd] + ad;
            v = v > 0.0f ? v : NEG_SLOPE * v;
            p = __expf(v);
        }
        den += p;
        if (r >= 9)      p1_batch<16>(s, p, h, lane, acc0, acc1);
        else if (r >= 5) p1_batch<8>(s, p, h, lane, acc0, acc1);
        else             p1_batch<4>(s, p, h, lane, acc0, acc1);
    }
    // den: reduce across the 16 lanes of this head group
    den += __shfl_xor(den, 1, 16);
    den += __shfl_xor(den, 2, 16);
    den += __shfl_xor(den, 4, 16);
    den += __shfl_xor(den, 8, 16);

    float inv = 1.0f / den;                  // den>0: self-loop guaranteed
    float o0 = acc0 * inv + b1[lane * 2];
    float o1 = acc1 * inv + b1[lane * 2 + 1];
    o0 = o0 > 0.0f ? o0 : expm1f(o0);
    o1 = o1 > 0.0f ? o1 : expm1f(o1);
    *(__half2*)(hact + (size_t)d * 128 + lane * 2) = __floats2half2_rn(o0, o1);
}

// ---- pull L2 batch body ----
template <int NB>
static __device__ __forceinline__ void p2_batch(int s, float p, const __half* __restrict__ h,
                                                int lane, float& acc) {
    int su[NB];
#pragma unroll
    for (int u = 0; u < NB; ++u) su[u] = __shfl(s, u, 16);
    __half g[NB];
#pragma unroll
    for (int u = 0; u < NB; ++u) g[u] = h[(size_t)su[u] * 32 + lane];
    float pu[NB];
#pragma unroll
    for (int u = 0; u < NB; ++u) pu[u] = __shfl(p, u, 16);
#pragma unroll
    for (int u = 0; u < NB; ++u) acc += pu[u] * __half2float(g[u]);
}

// ---- pull aggregation L2 (H=1,C=32) + fused column-mean ----
// Grid-stride over dsts; column partials in registers -> LDS reduce -> 32
// device-scope atomics per block. NO per-block __threadfence: on gfx950 a
// device fence lowers to L2 writeback/inv (non-coherent XCD L2s) and 2048 of
// them serialized the whole kernel (R4: 171 us, everything idle). The final
// readout is a separate dispatch; cross-kernel visibility comes from the
// runtime's dispatch-boundary release/acquire.
__global__ __launch_bounds__(256) void pull_agg2_k(const int* __restrict__ deg,
                                                   const unsigned short* __restrict__ col,
                                                   const float* __restrict__ asrc,
                                                   const float* __restrict__ adst,
                                                   const __half* __restrict__ h,
                                                   float* __restrict__ gsum, int N) {
    const int tid = threadIdx.x;
    const int lane = tid & 31;
    const int el = lane & 15;
    const int gloc = tid >> 5;                   // 8 dst-groups per block
    float csum = 0.0f;
    for (int d = blockIdx.x * 8 + gloc; d < N; d += gridDim.x * 8) {
        const float ad = adst[d];
        const unsigned short* cl = col + d * CAP;
        int cnt = deg[d]; if (cnt > CAP) cnt = CAP;
        float acc = 0.0f, den = 0.0f;
        for (int i = 0; i < cnt; i += 16) {
            const int r = cnt - i;
            int s = 0; float p = 0.0f;
            if (el < r) {
                s = cl[i + el];
                float v = asrc[s] + ad;
                v = v > 0.0f ? v : NEG_SLOPE * v;
                p = __expf(v);
            }
            den += p;                            // both halves identical; reduce width 16
            if (r >= 9)      p2_batch<16>(s, p, h, lane, acc);
            else if (r >= 5) p2_batch<8>(s, p, h, lane, acc);
            else             p2_batch<4>(s, p, h, lane, acc);
        }
        den += __shfl_xor(den, 1, 16);
        den += __shfl_xor(den, 2, 16);
        den += __shfl_xor(den, 4, 16);
        den += __shfl_xor(den, 8, 16);
        csum += acc / den;
    }
    __shared__ float lds[256];
    lds[tid] = csum;
    __syncthreads();
    if (tid < 32) {
        float s2 = 0.0f;
#pragma unroll
        for (int g = 0; g < 8; ++g) s2 += lds[g * 32 + tid];
        atomAdd(&gsum[tid], s2);
    }
}

__global__ void final_k(const float* __restrict__ gsum, const float* __restrict__ b2w,
                        const float* __restrict__ linW, const float* __restrict__ linb,
                        float* __restrict__ out, int N) {
    if (threadIdx.x != 0 || blockIdx.x != 0) return;
    float g[32];
#pragma unroll
    for (int c = 0; c < 32; ++c) g[c] = gsum[c] / (float)N + b2w[c];
    float lo[3];
#pragma unroll
    for (int j = 0; j < 3; ++j) {
        float acc = linb[j];
#pragma unroll
        for (int c = 0; c < 32; ++c) acc += g[c] * linW[c * 3 + j];
        lo[j] = acc;
    }
    float mx = fmaxf(lo[0], fmaxf(lo[1], lo[2]));
    float ex[3], se = 0.0f;
#pragma unroll
    for (int j = 0; j < 3; ++j) { ex[j] = __expf(lo[j] - mx); se += ex[j]; }
#pragma unroll
    for (int j = 0; j < 3; ++j) out[j] = ex[j] / se;
}

extern "C" void kernel_launch(void* const* d_in, const int* in_sizes, int n_in,
                              void* d_out, int out_size, void* d_ws, size_t ws_size,
                              hipStream_t stream) {
    const float* x    = (const float*)d_in[0];
    const float* W1   = (const float*)d_in[1];
    const float* as1w = (const float*)d_in[2];
    const float* ad1w = (const float*)d_in[3];
    const float* b1   = (const float*)d_in[4];
    const float* W2   = (const float*)d_in[5];
    const float* as2w = (const float*)d_in[6];
    const float* ad2w = (const float*)d_in[7];
    const float* b2w  = (const float*)d_in[8];
    const float* linW = (const float*)d_in[9];
    const float* linb = (const float*)d_in[10];
    const int*   ei   = (const int*)d_in[11];

    const int N = in_sizes[0] / 64;       // 50000
    const int E = in_sizes[11] / 2;       // 800000
    const int CAPB = (E + N) / 8 + 8192;  // per-slice bucket capacity

    float* ws = (float*)d_ws;
    __half* h1h   = (__half*)ws;                         // N*128 halves
    __half* hacth = (__half*)(ws + (size_t)N * 64);      // N*128 halves
    float* asrc1 = ws + (size_t)N * 128;                 // N*4
    float* adst1 = asrc1 + (size_t)N * 4;                // N*4
    float* asrc2 = adst1 + (size_t)N * 4;                // N
    float* adst2 = asrc2 + (size_t)N;                    // N
    float* gsum  = adst2 + (size_t)N;                    // 32
    int* cur     = (int*)(gsum + 33);                    // 8 bucket cursors
    int* deg     = cur + 8;                              // N
    unsigned short* col = (unsigned short*)(deg + N);    // N*CAP ushorts
    unsigned int* bkt = (unsigned int*)(col + (size_t)N * CAP);  // 8*CAPB
    // layer-2 alias inside h1h region (dead after pull_agg1):
    __half* h2h  = (__half*)ws;                          // N*32 halves

    auto cdiv = [](int a, int b) { return (a + b - 1) / b; };
    const int G1 = cdiv(N, 32);

    hipMemsetAsync(deg, 0, (size_t)N * sizeof(int), stream);
    hipMemsetAsync(gsum, 0, 41 * sizeof(float), stream);  // gsum + pad + cur

    // ---- single-pass edge partition into 8 XCD slice buckets ----
    partition_k<<<1024, 256, 0, stream>>>(ei, bkt, cur, E, N, CAPB);

    // ---- gemm1 || XCD-local bucket scatter (one dispatch) ----
    ka_k<<<G1 + SCATB, 256, 0, stream>>>(x, W1, as1w, ad1w, h1h, asrc1, adst1,
                                         bkt, cur, deg, col, N, G1, CAPB);

    // ---- layer 1 aggregation ----
    pull_agg1_k<<<cdiv(N, 4), 256, 0, stream>>>(deg, col, asrc1, adst1, h1h, b1, hacth, N);

    // ---- layer 2 ----
    gemm2_k<<<cdiv(N, 128), 256, 0, stream>>>(hacth, W2, as2w, ad2w, h2h, asrc2, adst2, N);
    pull_agg2_k<<<2048, 256, 0, stream>>>(deg, col, asrc2, adst2, h2h, gsum, N);

    // ---- readout ----
    final_k<<<1, 64, 0, stream>>>(gsum, b2w, linW, linb, (float*)d_out, N);
}

// Round 6
// 252.461 us; speedup vs baseline: 1.5493x; 1.1027x over previous
//
#include <hip/hip_runtime.h>
#include <hip/hip_fp16.h>
#include <math.h>

#define NEG_SLOPE 0.2f
#define CAP 64    // slots per dst; deg ~ Poisson(17), P(deg>64) ~ e^-41 per node
#define SCB 2048  // scatter blocks: 4 slice-groups x 512 blocks

static __device__ __forceinline__ void atomAdd(float* a, float v) {
    unsafeAtomicAdd(a, v);
}

// Edge-layout probe: int64 indices (<2^31) have all-zero odd 32-bit words.
static __device__ __forceinline__ bool edges_are_i64(const int* __restrict__ ei) {
    return (ei[1] | ei[3] | ei[5] | ei[7]) == 0;
}
static __device__ __forceinline__ int ldsrc(const int* __restrict__ ei, int e, int E, bool i64) {
    return i64 ? ei[2 * e] : ei[e];
}
static __device__ __forceinline__ int lddst(const int* __restrict__ ei, int e, int E, bool i64) {
    return i64 ? ei[2 * (E + e)] : ei[E + e];
}

// ---- sliced slot-CSR scatter (R2 config: best measured) ----
__global__ __launch_bounds__(256) void scatter_k(const int* __restrict__ ei,
                                                 int* __restrict__ deg,
                                                 int* __restrict__ col, int E, int N) {
    const int tid = threadIdx.x;
    const int grp = blockIdx.x & 3;
    const int bin = blockIdx.x >> 2;
    const int nb  = gridDim.x >> 2;
    const bool i64 = edges_are_i64(ei);
    const int ET = E + N;
    const int d0 = (int)((long long)grp * N / 4);
    const int d1 = (int)((long long)(grp + 1) * N / 4);
    for (int e = bin * 256 + tid; e < ET; e += nb * 256) {
        int s, d;
        if (e < E) { s = ldsrc(ei, e, E, i64); d = lddst(ei, e, E, i64); }
        else       { s = d = e - E; }
        if (d >= d0 && d < d1) {
            int pos = atomicAdd(&deg[d], 1);
            if (pos < CAP) col[d * CAP + pos] = s;
        }
    }
}

// ---- gemm1: 4x4 register tile, 32-row blocks, fused att logits, fp16 out ----
__global__ __launch_bounds__(256, 4) void gemm1_k(const float* __restrict__ x,
                                                  const float* __restrict__ W,
                                                  const float* __restrict__ aws,
                                                  const float* __restrict__ awd,
                                                  __half* __restrict__ h,
                                                  float* __restrict__ as_,
                                                  float* __restrict__ ad_, int N) {
    __shared__ float Ws[64 * 128];   // 32 KB, [k][j]
    __shared__ float xs[32 * 64];    // 8 KB, [row][k]
    const int tid = threadIdx.x;
    const int cg = tid & 31, rg = tid >> 5;
    const int r0 = blockIdx.x * 32;
#pragma unroll 1
    for (int i = tid; i < 8192; i += 256) Ws[i] = W[i];
    {
        const float* src = x + (size_t)r0 * 64;
        const int limit = (N - r0) * 64;
#pragma unroll 1
        for (int i = tid * 4; i < 2048; i += 1024) {
            float4 v = (i < limit) ? *(const float4*)(src + i) : make_float4(0, 0, 0, 0);
            *(float4*)(xs + i) = v;
        }
    }
    __syncthreads();

    float acc[4][4] = {};
#pragma unroll 2
    for (int k = 0; k < 64; k += 4) {
        float4 w0 = *(const float4*)(Ws + (k + 0) * 128 + cg * 4);
        float4 w1 = *(const float4*)(Ws + (k + 1) * 128 + cg * 4);
        float4 w2 = *(const float4*)(Ws + (k + 2) * 128 + cg * 4);
        float4 w3 = *(const float4*)(Ws + (k + 3) * 128 + cg * 4);
        float4 xv[4];
#pragma unroll
        for (int q = 0; q < 4; ++q) xv[q] = *(const float4*)(xs + (rg * 4 + q) * 64 + k);
#pragma unroll
        for (int q = 0; q < 4; ++q) {
            float4 xq = xv[q];
            acc[q][0] += xq.x * w0.x + xq.y * w1.x + xq.z * w2.x + xq.w * w3.x;
            acc[q][1] += xq.x * w0.y + xq.y * w1.y + xq.z * w2.y + xq.w * w3.y;
            acc[q][2] += xq.x * w0.z + xq.y * w1.z + xq.z * w2.z + xq.w * w3.z;
            acc[q][3] += xq.x * w0.w + xq.y * w1.w + xq.z * w2.w + xq.w * w3.w;
        }
    }

    const int jbase = cg * 4;
    const int head = cg >> 3;
    const float a0 = aws[jbase], a1 = aws[jbase + 1], a2 = aws[jbase + 2], a3 = aws[jbase + 3];
    const float d0 = awd[jbase], d1 = awd[jbase + 1], d2 = awd[jbase + 2], d3 = awd[jbase + 3];
    float ps[4], pd[4];
#pragma unroll
    for (int q = 0; q < 4; ++q) {
        ps[q] = acc[q][0] * a0 + acc[q][1] * a1 + acc[q][2] * a2 + acc[q][3] * a3;
        pd[q] = acc[q][0] * d0 + acc[q][1] * d1 + acc[q][2] * d2 + acc[q][3] * d3;
        int row = r0 + rg * 4 + q;
        if (row < N) {
            __half hv[4];
            hv[0] = __float2half(acc[q][0]); hv[1] = __float2half(acc[q][1]);
            hv[2] = __float2half(acc[q][2]); hv[3] = __float2half(acc[q][3]);
            *(uint2*)(h + (size_t)row * 128 + jbase) = *(uint2*)hv;
        }
    }
#pragma unroll
    for (int off = 4; off; off >>= 1) {
#pragma unroll
        for (int q = 0; q < 4; ++q) {
            ps[q] += __shfl_down(ps[q], off, 8);
            pd[q] += __shfl_down(pd[q], off, 8);
        }
    }
    if ((cg & 7) == 0) {
#pragma unroll
        for (int q = 0; q < 4; ++q) {
            int row = r0 + rg * 4 + q;
            if (row < N) { as_[row * 4 + head] = ps[q]; ad_[row * 4 + head] = pd[q]; }
        }
    }
}

// ---- pull L1 batch body: 16 outstanding gathers, straight-line ----
template <int NB>
static __device__ __forceinline__ void p1_batch(int s, float p, const __half* __restrict__ h,
                                                int lane, float& acc0, float& acc1) {
    int su[NB];
#pragma unroll
    for (int u = 0; u < NB; ++u) su[u] = __shfl(s, u, 16);
    __half2 g[NB];
#pragma unroll
    for (int u = 0; u < NB; ++u) g[u] = *(const __half2*)(h + (size_t)su[u] * 128 + lane * 2);
    float pu[NB];
#pragma unroll
    for (int u = 0; u < NB; ++u) pu[u] = __shfl(p, u, 16);
#pragma unroll
    for (int u = 0; u < NB; ++u) {
        float2 gf = __half22float2(g[u]);
        acc0 += pu[u] * gf.x; acc1 += pu[u] * gf.y;
    }
}

// ---- pg1_k: pull_agg1 fused with gemm2 (row-local dependency) ----
// 8 waves/block, 1 dst per wave. Phase A: R2's pull_agg1 per wave, activation
// row kept in LDS (hact global array eliminated: saves 25.6 MB write + 25.6 MB
// read + one dispatch). Phase B: wave-internal GEMV against transposed+padded
// W2 in LDS (float4 ds reads: 32 LDS instrs/wave instead of 128 scalar).
// R5 lesson respected: both phases are LDS-using, 512-thread, same-occupancy.
__global__ __launch_bounds__(512) void pg1_k(const int* __restrict__ deg,
                                             const int* __restrict__ col,
                                             const float* __restrict__ asrc,
                                             const float* __restrict__ adst,
                                             const __half* __restrict__ h,
                                             const float* __restrict__ b1,
                                             const float* __restrict__ W2,
                                             const float* __restrict__ aws2,
                                             const float* __restrict__ awd2,
                                             __half* __restrict__ h2,
                                             float* __restrict__ as2_,
                                             float* __restrict__ ad2_, int N) {
    __shared__ float W2t[32 * 132];   // 16.9 KB: W2 transposed [j][k], stride 132
    __shared__ float hrow[8][128];    // 4 KB: per-wave activation row
    const int tid = threadIdx.x;
    // cooperative transpose-load of W2 [128][32] -> W2t [32][132]
    for (int i = tid; i < 4096; i += 512) {
        int k = i >> 5, j = i & 31;
        W2t[j * 132 + k] = W2[i];
    }
    const int w = tid >> 6;
    const int lane = tid & 63;
    const int d = blockIdx.x * 8 + w;
    const int hd = lane >> 4;     // head
    const int el = lane & 15;     // edge slot within 16-edge batch
    if (d < N) {
        const float ad = adst[d * 4 + hd];
        const int* cl = col + d * CAP;
        int cnt = deg[d]; if (cnt > CAP) cnt = CAP;
        float acc0 = 0.0f, acc1 = 0.0f, den = 0.0f;
        for (int i = 0; i < cnt; i += 16) {
            const int r = cnt - i;               // wave-uniform
            int s = 0; float p = 0.0f;
            if (el < r) {
                s = cl[i + el];
                float v = asrc[s * 4 + hd] + ad;
                v = v > 0.0f ? v : NEG_SLOPE * v;
                p = __expf(v);
            }
            den += p;
            p1_batch<16>(s, p, h, lane, acc0, acc1);
        }
        den += __shfl_xor(den, 1, 16);
        den += __shfl_xor(den, 2, 16);
        den += __shfl_xor(den, 4, 16);
        den += __shfl_xor(den, 8, 16);
        float inv = 1.0f / den;                  // den>0: self-loop guaranteed
        float o0 = acc0 * inv + b1[lane * 2];
        float o1 = acc1 * inv + b1[lane * 2 + 1];
        o0 = o0 > 0.0f ? o0 : expm1f(o0);
        o1 = o1 > 0.0f ? o1 : expm1f(o1);
        hrow[w][lane * 2]     = o0;
        hrow[w][lane * 2 + 1] = o1;
    }
    __syncthreads();                             // W2t ready; hrow ordered too
    if (d < N) {
        const int j = lane & 31, hf = lane >> 5; // 2 lanes per output col
        const float4* hr4 = (const float4*)(hrow[w] + hf * 64);
        const float*  wt  = W2t + j * 132 + hf * 64;
        float sum = 0.0f;
#pragma unroll
        for (int k4 = 0; k4 < 16; ++k4) {
            float4 hv = hr4[k4];                 // broadcast (same addr in half)
            float4 wv = *(const float4*)(wt + k4 * 4);
            sum += hv.x * wv.x + hv.y * wv.y + hv.z * wv.z + hv.w * wv.w;
        }
        sum += __shfl_xor(sum, 32, 64);          // combine the two k-halves
        if (lane < 32) h2[(size_t)d * 32 + j] = __float2half(sum);
        float t = sum * aws2[j];
        float u = sum * awd2[j];
#pragma unroll
        for (int off = 16; off; off >>= 1) {
            t += __shfl_xor(t, off, 32);
            u += __shfl_xor(u, off, 32);
        }
        if (lane == 0) { as2_[d] = t; ad2_[d] = u; }
    }
}

// ---- pull L2 batch body ----
template <int NB>
static __device__ __forceinline__ void p2_batch(int s, float p, const __half* __restrict__ h,
                                                int lane, float& acc) {
    int su[NB];
#pragma unroll
    for (int u = 0; u < NB; ++u) su[u] = __shfl(s, u, 16);
    __half g[NB];
#pragma unroll
    for (int u = 0; u < NB; ++u) g[u] = h[(size_t)su[u] * 32 + lane];
    float pu[NB];
#pragma unroll
    for (int u = 0; u < NB; ++u) pu[u] = __shfl(p, u, 16);
#pragma unroll
    for (int u = 0; u < NB; ++u) acc += pu[u] * __half2float(g[u]);
}

// ---- pull aggregation L2 (H=1,C=32) + fused column-mean (R2 version) ----
__global__ __launch_bounds__(256) void pull_agg2_k(const int* __restrict__ deg,
                                                   const int* __restrict__ col,
                                                   const float* __restrict__ asrc,
                                                   const float* __restrict__ adst,
                                                   const __half* __restrict__ h,
                                                   float* __restrict__ gsum, int N) {
    const int tid = threadIdx.x;
    const int lane = tid & 31;
    const int el = lane & 15;
    const int gloc = tid >> 5;                   // 8 dst-groups per block
    float csum = 0.0f;
    for (int d = blockIdx.x * 8 + gloc; d < N; d += gridDim.x * 8) {
        const float ad = adst[d];
        const int* cl = col + d * CAP;
        int cnt = deg[d]; if (cnt > CAP) cnt = CAP;
        float acc = 0.0f, den = 0.0f;
        for (int i = 0; i < cnt; i += 16) {
            const int r = cnt - i;
            int s = 0; float p = 0.0f;
            if (el < r) {
                s = cl[i + el];
                float v = asrc[s] + ad;
                v = v > 0.0f ? v : NEG_SLOPE * v;
                p = __expf(v);
            }
            den += p;                            // both halves identical; reduce width 16
            p2_batch<16>(s, p, h, lane, acc);
        }
        den += __shfl_xor(den, 1, 16);
        den += __shfl_xor(den, 2, 16);
        den += __shfl_xor(den, 4, 16);
        den += __shfl_xor(den, 8, 16);
        csum += acc / den;
    }
    __shared__ float lds[256];
    lds[tid] = csum;
    __syncthreads();
    if (tid < 32) {
        float s2 = 0.0f;
#pragma unroll
        for (int g = 0; g < 8; ++g) s2 += lds[g * 32 + tid];
        atomAdd(&gsum[tid], s2);
    }
}

__global__ void final_k(const float* __restrict__ gsum, const float* __restrict__ b2w,
                        const float* __restrict__ linW, const float* __restrict__ linb,
                        float* __restrict__ out, int N) {
    if (threadIdx.x != 0 || blockIdx.x != 0) return;
    float g[32];
#pragma unroll
    for (int c = 0; c < 32; ++c) g[c] = gsum[c] / (float)N + b2w[c];
    float lo[3];
#pragma unroll
    for (int j = 0; j < 3; ++j) {
        float acc = linb[j];
#pragma unroll
        for (int c = 0; c < 32; ++c) acc += g[c] * linW[c * 3 + j];
        lo[j] = acc;
    }
    float mx = fmaxf(lo[0], fmaxf(lo[1], lo[2]));
    float ex[3], se = 0.0f;
#pragma unroll
    for (int j = 0; j < 3; ++j) { ex[j] = __expf(lo[j] - mx); se += ex[j]; }
#pragma unroll
    for (int j = 0; j < 3; ++j) out[j] = ex[j] / se;
}

extern "C" void kernel_launch(void* const* d_in, const int* in_sizes, int n_in,
                              void* d_out, int out_size, void* d_ws, size_t ws_size,
                              hipStream_t stream) {
    const float* x    = (const float*)d_in[0];
    const float* W1   = (const float*)d_in[1];
    const float* as1w = (const float*)d_in[2];
    const float* ad1w = (const float*)d_in[3];
    const float* b1   = (const float*)d_in[4];
    const float* W2   = (const float*)d_in[5];
    const float* as2w = (const float*)d_in[6];
    const float* ad2w = (const float*)d_in[7];
    const float* b2w  = (const float*)d_in[8];
    const float* linW = (const float*)d_in[9];
    const float* linb = (const float*)d_in[10];
    const int*   ei   = (const int*)d_in[11];

    const int N = in_sizes[0] / 64;       // 50000
    const int E = in_sizes[11] / 2;       // 800000

    float* ws = (float*)d_ws;
    __half* h1h  = (__half*)ws;                          // N*128 halves
    float* asrc1 = ws + (size_t)N * 64;                  // N*4
    float* adst1 = asrc1 + (size_t)N * 4;                // N*4
    __half* h2h  = (__half*)(adst1 + (size_t)N * 4);     // N*32 halves (own region:
                                                         // written while h1h is read)
    float* asrc2 = adst1 + (size_t)N * 4 + (size_t)N * 16;  // N
    float* adst2 = asrc2 + (size_t)N;                    // N
    float* gsum  = adst2 + (size_t)N;                    // 32
    int* deg     = (int*)(gsum + 32);                    // N (adjacent: one memset)
    int* col     = deg + N;                              // N*CAP ints

    auto cdiv = [](int a, int b) { return (a + b - 1) / b; };

    // single merged memset: gsum (32 floats) + deg (N ints) are adjacent
    hipMemsetAsync(gsum, 0, (size_t)(32 + N) * sizeof(int), stream);

    // ---- slot-CSR build (R2 config) ----
    scatter_k<<<SCB, 256, 0, stream>>>(ei, deg, col, E, N);

    // ---- layer 1 GEMM ----
    gemm1_k<<<cdiv(N, 32), 256, 0, stream>>>(x, W1, as1w, ad1w, h1h, asrc1, adst1, N);

    // ---- layer 1 aggregation fused with layer 2 GEMM (hact eliminated) ----
    pg1_k<<<cdiv(N, 8), 512, 0, stream>>>(deg, col, asrc1, adst1, h1h, b1,
                                          W2, as2w, ad2w, h2h, asrc2, adst2, N);

    // ---- layer 2 aggregation + column-mean ----
    pull_agg2_k<<<2048, 256, 0, stream>>>(deg, col, asrc2, adst2, h2h, gsum, N);

    // ---- readout ----
    final_k<<<1, 64, 0, stream>>>(gsum, b2w, linW, linb, (float*)d_out, N);
}

// Round 7
// 242.664 us; speedup vs baseline: 1.6118x; 1.0404x over previous
//
#include <hip/hip_runtime.h>
#include <hip/hip_fp16.h>
#include <math.h>

#define NEG_SLOPE 0.2f
#define CAP 64    // slots per dst; deg ~ Poisson(17), P(deg>64) ~ e^-41 per node
#define SCB 2048  // scatter blocks: 4 slice-groups x 512 blocks

static __device__ __forceinline__ void atomAdd(float* a, float v) {
    unsafeAtomicAdd(a, v);
}

// Edge-layout probe: int64 indices (<2^31) have all-zero odd 32-bit words.
static __device__ __forceinline__ bool edges_are_i64(const int* __restrict__ ei) {
    return (ei[1] | ei[3] | ei[5] | ei[7]) == 0;
}
static __device__ __forceinline__ int ldsrc(const int* __restrict__ ei, int e, int E, bool i64) {
    return i64 ? ei[2 * e] : ei[e];
}
static __device__ __forceinline__ int lddst(const int* __restrict__ ei, int e, int E, bool i64) {
    return i64 ? ei[2 * (E + e)] : ei[E + e];
}

// ---- sliced slot-CSR scatter (R2 config: best measured) ----
__global__ __launch_bounds__(256) void scatter_k(const int* __restrict__ ei,
                                                 int* __restrict__ deg,
                                                 int* __restrict__ col, int E, int N) {
    const int tid = threadIdx.x;
    const int grp = blockIdx.x & 3;
    const int bin = blockIdx.x >> 2;
    const int nb  = gridDim.x >> 2;
    const bool i64 = edges_are_i64(ei);
    const int ET = E + N;
    const int d0 = (int)((long long)grp * N / 4);
    const int d1 = (int)((long long)(grp + 1) * N / 4);
    for (int e = bin * 256 + tid; e < ET; e += nb * 256) {
        int s, d;
        if (e < E) { s = ldsrc(ei, e, E, i64); d = lddst(ei, e, E, i64); }
        else       { s = d = e - E; }
        if (d >= d0 && d < d1) {
            int pos = atomicAdd(&deg[d], 1);
            if (pos < CAP) col[d * CAP + pos] = s;
        }
    }
}

// ---- gemm1: 4x4 register tile, 32-row blocks, fused att logits, fp16 out ----
__global__ __launch_bounds__(256, 4) void gemm1_k(const float* __restrict__ x,
                                                  const float* __restrict__ W,
                                                  const float* __restrict__ aws,
                                                  const float* __restrict__ awd,
                                                  __half* __restrict__ h,
                                                  float* __restrict__ as_,
                                                  float* __restrict__ ad_, int N) {
    __shared__ float Ws[64 * 128];   // 32 KB, [k][j]
    __shared__ float xs[32 * 64];    // 8 KB, [row][k]
    const int tid = threadIdx.x;
    const int cg = tid & 31, rg = tid >> 5;
    const int r0 = blockIdx.x * 32;
#pragma unroll 1
    for (int i = tid; i < 8192; i += 256) Ws[i] = W[i];
    {
        const float* src = x + (size_t)r0 * 64;
        const int limit = (N - r0) * 64;
#pragma unroll 1
        for (int i = tid * 4; i < 2048; i += 1024) {
            float4 v = (i < limit) ? *(const float4*)(src + i) : make_float4(0, 0, 0, 0);
            *(float4*)(xs + i) = v;
        }
    }
    __syncthreads();

    float acc[4][4] = {};
#pragma unroll 2
    for (int k = 0; k < 64; k += 4) {
        float4 w0 = *(const float4*)(Ws + (k + 0) * 128 + cg * 4);
        float4 w1 = *(const float4*)(Ws + (k + 1) * 128 + cg * 4);
        float4 w2 = *(const float4*)(Ws + (k + 2) * 128 + cg * 4);
        float4 w3 = *(const float4*)(Ws + (k + 3) * 128 + cg * 4);
        float4 xv[4];
#pragma unroll
        for (int q = 0; q < 4; ++q) xv[q] = *(const float4*)(xs + (rg * 4 + q) * 64 + k);
#pragma unroll
        for (int q = 0; q < 4; ++q) {
            float4 xq = xv[q];
            acc[q][0] += xq.x * w0.x + xq.y * w1.x + xq.z * w2.x + xq.w * w3.x;
            acc[q][1] += xq.x * w0.y + xq.y * w1.y + xq.z * w2.y + xq.w * w3.y;
            acc[q][2] += xq.x * w0.z + xq.y * w1.z + xq.z * w2.z + xq.w * w3.z;
            acc[q][3] += xq.x * w0.w + xq.y * w1.w + xq.z * w2.w + xq.w * w3.w;
        }
    }

    const int jbase = cg * 4;
    const int head = cg >> 3;
    const float a0 = aws[jbase], a1 = aws[jbase + 1], a2 = aws[jbase + 2], a3 = aws[jbase + 3];
    const float d0 = awd[jbase], d1 = awd[jbase + 1], d2 = awd[jbase + 2], d3 = awd[jbase + 3];
    float ps[4], pd[4];
#pragma unroll
    for (int q = 0; q < 4; ++q) {
        ps[q] = acc[q][0] * a0 + acc[q][1] * a1 + acc[q][2] * a2 + acc[q][3] * a3;
        pd[q] = acc[q][0] * d0 + acc[q][1] * d1 + acc[q][2] * d2 + acc[q][3] * d3;
        int row = r0 + rg * 4 + q;
        if (row < N) {
            __half hv[4];
            hv[0] = __float2half(acc[q][0]); hv[1] = __float2half(acc[q][1]);
            hv[2] = __float2half(acc[q][2]); hv[3] = __float2half(acc[q][3]);
            *(uint2*)(h + (size_t)row * 128 + jbase) = *(uint2*)hv;
        }
    }
#pragma unroll
    for (int off = 4; off; off >>= 1) {
#pragma unroll
        for (int q = 0; q < 4; ++q) {
            ps[q] += __shfl_down(ps[q], off, 8);
            pd[q] += __shfl_down(pd[q], off, 8);
        }
    }
    if ((cg & 7) == 0) {
#pragma unroll
        for (int q = 0; q < 4; ++q) {
            int row = r0 + rg * 4 + q;
            if (row < N) { as_[row * 4 + head] = ps[q]; ad_[row * 4 + head] = pd[q]; }
        }
    }
}

// ---- gemm2: 4x4 register tile, 128-row blocks, fp32 hact in, fp16 out ----
__global__ __launch_bounds__(256, 4) void gemm2_k(const float* __restrict__ hact,
                                                  const float* __restrict__ W,
                                                  const float* __restrict__ aws,
                                                  const float* __restrict__ awd,
                                                  __half* __restrict__ h2,
                                                  float* __restrict__ as_,
                                                  float* __restrict__ ad_, int N) {
    __shared__ float Ws[128 * 32];     // 16 KB, [k][j]
    __shared__ float xs[128 * 68];     // 34 KB, [row][k], stride 68
    const int tid = threadIdx.x;
    const int cg = tid & 7, rg = tid >> 3;
    const int r0 = blockIdx.x * 128;
    for (int i = tid; i < 4096; i += 256) Ws[i] = W[i];

    float acc[4][4] = {};
#pragma unroll 1
    for (int p = 0; p < 2; ++p) {
        __syncthreads();
#pragma unroll 2
        for (int i = tid * 4; i < 8192; i += 1024) {
            int row = i >> 6, kk = i & 63;
            float4 v = (r0 + row < N)
                ? *(const float4*)(hact + (size_t)(r0 + row) * 128 + p * 64 + kk)
                : make_float4(0, 0, 0, 0);
            *(float4*)(xs + row * 68 + kk) = v;
        }
        __syncthreads();
#pragma unroll 2
        for (int k = 0; k < 64; k += 4) {
            float4 w0 = *(const float4*)(Ws + (p * 64 + k + 0) * 32 + cg * 4);
            float4 w1 = *(const float4*)(Ws + (p * 64 + k + 1) * 32 + cg * 4);
            float4 w2 = *(const float4*)(Ws + (p * 64 + k + 2) * 32 + cg * 4);
            float4 w3 = *(const float4*)(Ws + (p * 64 + k + 3) * 32 + cg * 4);
            float4 xv[4];
#pragma unroll
            for (int q = 0; q < 4; ++q) xv[q] = *(const float4*)(xs + (rg * 4 + q) * 68 + k);
#pragma unroll
            for (int q = 0; q < 4; ++q) {
                float4 xq = xv[q];
                acc[q][0] += xq.x * w0.x + xq.y * w1.x + xq.z * w2.x + xq.w * w3.x;
                acc[q][1] += xq.x * w0.y + xq.y * w1.y + xq.z * w2.y + xq.w * w3.y;
                acc[q][2] += xq.x * w0.z + xq.y * w1.z + xq.z * w2.z + xq.w * w3.z;
                acc[q][3] += xq.x * w0.w + xq.y * w1.w + xq.z * w2.w + xq.w * w3.w;
            }
        }
    }

    const int jbase = cg * 4;
    const float a0 = aws[jbase], a1 = aws[jbase + 1], a2 = aws[jbase + 2], a3 = aws[jbase + 3];
    const float d0 = awd[jbase], d1 = awd[jbase + 1], d2 = awd[jbase + 2], d3 = awd[jbase + 3];
    float ps[4], pd[4];
#pragma unroll
    for (int q = 0; q < 4; ++q) {
        ps[q] = acc[q][0] * a0 + acc[q][1] * a1 + acc[q][2] * a2 + acc[q][3] * a3;
        pd[q] = acc[q][0] * d0 + acc[q][1] * d1 + acc[q][2] * d2 + acc[q][3] * d3;
        int row = r0 + rg * 4 + q;
        if (row < N) {
            __half hv[4];
            hv[0] = __float2half(acc[q][0]); hv[1] = __float2half(acc[q][1]);
            hv[2] = __float2half(acc[q][2]); hv[3] = __float2half(acc[q][3]);
            *(uint2*)(h2 + (size_t)row * 32 + jbase) = *(uint2*)hv;
        }
    }
#pragma unroll
    for (int off = 4; off; off >>= 1) {
#pragma unroll
        for (int q = 0; q < 4; ++q) {
            ps[q] += __shfl_down(ps[q], off, 8);
            pd[q] += __shfl_down(pd[q], off, 8);
        }
    }
    if (cg == 0) {
#pragma unroll
        for (int q = 0; q < 4; ++q) {
            int row = r0 + rg * 4 + q;
            if (row < N) { as_[row] = ps[q]; ad_[row] = pd[q]; }
        }
    }
}

// ---- pull L1 wide batch: ST load steps, 2 rows (8B/lane) per step ----
// Lanes 0-31 handle edge 2u, lanes 32-63 edge 2u+1; each lane covers 4
// channels (cl4 = lane&31). Halves the VMEM and DS instruction count per
// edge vs the 4B/lane version.
template <int ST>
static __device__ __forceinline__ void p1_wide(int s, float p, const __half* __restrict__ h,
                                               int half, int cl4, int hdA,
                                               float& a0, float& a1, float& a2, float& a3) {
    int su[ST]; float pu[ST]; uint2 g[ST];
#pragma unroll
    for (int u = 0; u < ST; ++u) su[u] = __shfl(s, 2 * u + half);
#pragma unroll
    for (int u = 0; u < ST; ++u) g[u] = *(const uint2*)(h + (size_t)su[u] * 128 + cl4 * 4);
#pragma unroll
    for (int u = 0; u < ST; ++u) pu[u] = __shfl(p, hdA * 16 + 2 * u + half);
#pragma unroll
    for (int u = 0; u < ST; ++u) {
        float2 f0 = __half22float2(*(const __half2*)&g[u].x);
        float2 f1 = __half22float2(*(const __half2*)&g[u].y);
        a0 += pu[u] * f0.x; a1 += pu[u] * f0.y;
        a2 += pu[u] * f1.x; a3 += pu[u] * f1.y;
    }
}

// ---- pull aggregation L1: widened gathers (2 rows / load), fp32 hact out ----
// p-compute layout unchanged (el=lane&15 edge, hd=lane>>4 head). Accumulator
// layout: lane covers channels 4*cl4..4*cl4+3 of head hdA=cl4>>3; even edges
// accumulate in lanes<32, odd in lanes>=32; one shfl_xor(32) combines.
__global__ __launch_bounds__(256) void pull_agg1_k(const int* __restrict__ deg,
                                                   const int* __restrict__ col,
                                                   const float* __restrict__ asrc,
                                                   const float* __restrict__ adst,
                                                   const __half* __restrict__ h,
                                                   const float* __restrict__ b1,
                                                   float* __restrict__ hact, int N) {
    int wave = (blockIdx.x * 256 + threadIdx.x) >> 6;
    int lane = threadIdx.x & 63;
    if (wave >= N) return;
    const int d = wave;
    const int hd = lane >> 4;        // head (p-compute)
    const int el = lane & 15;        // edge slot (p-compute)
    const int half = lane >> 5;      // which of 2 rows per load step
    const int cl4 = lane & 31;       // channel group (4 ch)
    const int hdA = cl4 >> 3;        // head (accumulation)
    const float ad = adst[d * 4 + hd];
    const int* cl = col + d * CAP;
    int cnt = deg[d]; if (cnt > CAP) cnt = CAP;
    float a0 = 0, a1 = 0, a2 = 0, a3 = 0, den = 0;

    for (int i = 0; i < cnt; i += 16) {
        const int r = cnt - i;               // wave-uniform
        int s = 0; float p = 0.0f;
        if (el < r) {
            s = cl[i + el];
            float v = asrc[s * 4 + hd] + ad;
            v = v > 0.0f ? v : NEG_SLOPE * v;
            p = __expf(v);
        }
        den += p;
        if (r > 8)      p1_wide<8>(s, p, h, half, cl4, hdA, a0, a1, a2, a3);
        else if (r > 4) p1_wide<4>(s, p, h, half, cl4, hdA, a0, a1, a2, a3);
        else            p1_wide<2>(s, p, h, half, cl4, hdA, a0, a1, a2, a3);
    }
    // den: reduce across 16 lanes of each head group, then pull hdA's value
    den += __shfl_xor(den, 1, 16);
    den += __shfl_xor(den, 2, 16);
    den += __shfl_xor(den, 4, 16);
    den += __shfl_xor(den, 8, 16);
    float denA = __shfl(den, hdA * 16);
    // combine even-edge (lanes<32) and odd-edge (lanes>=32) partials
    a0 += __shfl_xor(a0, 32);
    a1 += __shfl_xor(a1, 32);
    a2 += __shfl_xor(a2, 32);
    a3 += __shfl_xor(a3, 32);
    if (half == 0) {
        float inv = 1.0f / denA;             // den>0: self-loop guaranteed
        float o0 = a0 * inv + b1[cl4 * 4 + 0];
        float o1 = a1 * inv + b1[cl4 * 4 + 1];
        float o2 = a2 * inv + b1[cl4 * 4 + 2];
        float o3 = a3 * inv + b1[cl4 * 4 + 3];
        o0 = o0 > 0.0f ? o0 : expm1f(o0);
        o1 = o1 > 0.0f ? o1 : expm1f(o1);
        o2 = o2 > 0.0f ? o2 : expm1f(o2);
        o3 = o3 > 0.0f ? o3 : expm1f(o3);
        *(float4*)(hact + (size_t)d * 128 + cl4 * 4) = make_float4(o0, o1, o2, o3);
    }
}

// ---- pull L2 batch body (R2 version) ----
template <int NB>
static __device__ __forceinline__ void p2_batch(int s, float p, const __half* __restrict__ h,
                                                int lane, float& acc) {
    int su[NB];
#pragma unroll
    for (int u = 0; u < NB; ++u) su[u] = __shfl(s, u, 16);
    __half g[NB];
#pragma unroll
    for (int u = 0; u < NB; ++u) g[u] = h[(size_t)su[u] * 32 + lane];
    float pu[NB];
#pragma unroll
    for (int u = 0; u < NB; ++u) pu[u] = __shfl(p, u, 16);
#pragma unroll
    for (int u = 0; u < NB; ++u) acc += pu[u] * __half2float(g[u]);
}

// ---- pull aggregation L2 (H=1,C=32) + fused column-mean (R2 version) ----
__global__ __launch_bounds__(256) void pull_agg2_k(const int* __restrict__ deg,
                                                   const int* __restrict__ col,
                                                   const float* __restrict__ asrc,
                                                   const float* __restrict__ adst,
                                                   const __half* __restrict__ h,
                                                   float* __restrict__ gsum, int N) {
    const int tid = threadIdx.x;
    const int lane = tid & 31;
    const int el = lane & 15;
    const int gloc = tid >> 5;                   // 8 dst-groups per block
    float csum = 0.0f;
    for (int d = blockIdx.x * 8 + gloc; d < N; d += gridDim.x * 8) {
        const float ad = adst[d];
        const int* cl = col + d * CAP;
        int cnt = deg[d]; if (cnt > CAP) cnt = CAP;
        float acc = 0.0f, den = 0.0f;
        for (int i = 0; i < cnt; i += 16) {
            const int r = cnt - i;
            int s = 0; float p = 0.0f;
            if (el < r) {
                s = cl[i + el];
                float v = asrc[s] + ad;
                v = v > 0.0f ? v : NEG_SLOPE * v;
                p = __expf(v);
            }
            den += p;                            // both halves identical; reduce width 16
            p2_batch<16>(s, p, h, lane, acc);
        }
        den += __shfl_xor(den, 1, 16);
        den += __shfl_xor(den, 2, 16);
        den += __shfl_xor(den, 4, 16);
        den += __shfl_xor(den, 8, 16);
        csum += acc / den;
    }
    __shared__ float lds[256];
    lds[tid] = csum;
    __syncthreads();
    if (tid < 32) {
        float s2 = 0.0f;
#pragma unroll
        for (int g = 0; g < 8; ++g) s2 += lds[g * 32 + tid];
        atomAdd(&gsum[tid], s2);
    }
}

__global__ void final_k(const float* __restrict__ gsum, const float* __restrict__ b2w,
                        const float* __restrict__ linW, const float* __restrict__ linb,
                        float* __restrict__ out, int N) {
    if (threadIdx.x != 0 || blockIdx.x != 0) return;
    float g[32];
#pragma unroll
    for (int c = 0; c < 32; ++c) g[c] = gsum[c] / (float)N + b2w[c];
    float lo[3];
#pragma unroll
    for (int j = 0; j < 3; ++j) {
        float acc = linb[j];
#pragma unroll
        for (int c = 0; c < 32; ++c) acc += g[c] * linW[c * 3 + j];
        lo[j] = acc;
    }
    float mx = fmaxf(lo[0], fmaxf(lo[1], lo[2]));
    float ex[3], se = 0.0f;
#pragma unroll
    for (int j = 0; j < 3; ++j) { ex[j] = __expf(lo[j] - mx); se += ex[j]; }
#pragma unroll
    for (int j = 0; j < 3; ++j) out[j] = ex[j] / se;
}

extern "C" void kernel_launch(void* const* d_in, const int* in_sizes, int n_in,
                              void* d_out, int out_size, void* d_ws, size_t ws_size,
                              hipStream_t stream) {
    const float* x    = (const float*)d_in[0];
    const float* W1   = (const float*)d_in[1];
    const float* as1w = (const float*)d_in[2];
    const float* ad1w = (const float*)d_in[3];
    const float* b1   = (const float*)d_in[4];
    const float* W2   = (const float*)d_in[5];
    const float* as2w = (const float*)d_in[6];
    const float* ad2w = (const float*)d_in[7];
    const float* b2w  = (const float*)d_in[8];
    const float* linW = (const float*)d_in[9];
    const float* linb = (const float*)d_in[10];
    const int*   ei   = (const int*)d_in[11];

    const int N = in_sizes[0] / 64;       // 50000
    const int E = in_sizes[11] / 2;       // 800000

    float* ws = (float*)d_ws;
    __half* h1h  = (__half*)ws;                          // N*128 halves
    float*  hact = ws + (size_t)N * 64;                  // N*128 fp32
    float* asrc1 = hact + (size_t)N * 128;               // N*4
    float* adst1 = asrc1 + (size_t)N * 4;                // N*4
    float* asrc2 = adst1 + (size_t)N * 4;                // N
    float* adst2 = asrc2 + (size_t)N;                    // N
    float* gsum  = adst2 + (size_t)N;                    // 32
    int* deg     = (int*)(gsum + 32);                    // N (adjacent: one memset)
    int* col     = deg + N;                              // N*CAP ints
    // layer-2 alias inside h1h region (dead after pull_agg1):
    __half* h2h  = (__half*)ws;                          // N*32 halves

    auto cdiv = [](int a, int b) { return (a + b - 1) / b; };

    // single merged memset: gsum (32 floats) + deg (N ints) are adjacent
    hipMemsetAsync(gsum, 0, (size_t)(32 + N) * sizeof(int), stream);

    // ---- slot-CSR build (R2 config) ----
    scatter_k<<<SCB, 256, 0, stream>>>(ei, deg, col, E, N);

    // ---- layer 1 ----
    gemm1_k<<<cdiv(N, 32), 256, 0, stream>>>(x, W1, as1w, ad1w, h1h, asrc1, adst1, N);
    pull_agg1_k<<<cdiv(N, 4), 256, 0, stream>>>(deg, col, asrc1, adst1, h1h, b1, hact, N);

    // ---- layer 2 ----
    gemm2_k<<<cdiv(N, 128), 256, 0, stream>>>(hact, W2, as2w, ad2w, h2h, asrc2, adst2, N);
    pull_agg2_k<<<2048, 256, 0, stream>>>(deg, col, asrc2, adst2, h2h, gsum, N);

    // ---- readout ----
    final_k<<<1, 64, 0, stream>>>(gsum, b2w, linW, linb, (float*)d_out, N);
}